// Round 1
// baseline (549.843 us; speedup 1.0000x reference)
//
#include <hip/hip_runtime.h>
#include <math.h>

#define B_ 32
#define C_ 256
#define H_ 28
#define W_ 28
#define NPIX 784
#define HK 14
#define NKPIX 196
#define CM 1024
#define EPS_ 1e-5f
#define LN_INVN (1.0f / (C_ * NPIX))

typedef __attribute__((ext_vector_type(8))) short short8;
typedef __attribute__((ext_vector_type(4))) short short4_;
typedef __attribute__((ext_vector_type(4))) float float4_;

__device__ __forceinline__ float gelu_f(float x) {
    return 0.5f * x * (1.0f + erff(x * 0.70710678118654752f));
}
__device__ __forceinline__ short f2bf(float f) {
    union { float f; unsigned u; } x; x.f = f;
    unsigned r = x.u + 0x7FFF + ((x.u >> 16) & 1);
    return (short)(r >> 16);
}
__device__ __forceinline__ float bf2f(short s) {
    union { unsigned u; float f; } x; x.u = ((unsigned)(unsigned short)s) << 16;
    return x.f;
}
// async global->LDS, 16B per lane; LDS dest is wave-uniform base + lane*16
__device__ __forceinline__ void gld16(const short* g, short* l) {
    __builtin_amdgcn_global_load_lds((const __attribute__((address_space(1))) void*)g,
                                     (__attribute__((address_space(3))) void*)l,
                                     16, 0, 0);
}

// ---- convert all 6 weight matrices to bf16 (layout [oc][k], k contiguous) ----
__global__ void wconv_kernel(const float* __restrict__ wq, const float* __restrict__ wk,
                             const float* __restrict__ wv, const float* __restrict__ wo,
                             const float* __restrict__ c1, const float* __restrict__ c2,
                             short* __restrict__ dst) {
    int idx = blockIdx.x * 256 + threadIdx.x;  // total 786432
    const float* src; int off;
    if (idx < 65536)       { src = wq; off = idx; }
    else if (idx < 131072) { src = wk; off = idx - 65536; }
    else if (idx < 196608) { src = wv; off = idx - 131072; }
    else if (idx < 262144) { src = wo; off = idx - 196608; }
    else if (idx < 524288) { src = c1; off = idx - 262144; }
    else                   { src = c2; off = idx - 524288; }
    dst[idx] = f2bf(src[off]);
}

// ---- prep for dwgelu: transpose dww to [tap][1024], fold dwb+BN2 to (sc,sh);
//      also zero the LN2 atomic-stat accumulator (runs before all GEMMs) ----
__global__ void dwprep_kernel(const float* __restrict__ dww, const float* __restrict__ dwb,
                              const float* __restrict__ g2, const float* __restrict__ b2,
                              const float* __restrict__ m2, const float* __restrict__ v2,
                              float* __restrict__ wt, float* __restrict__ sc2,
                              float* __restrict__ sh2, float* __restrict__ st2) {
    int cm = blockIdx.x * 256 + threadIdx.x;  // 1024
    if (blockIdx.x == 0 && threadIdx.x < 64) st2[threadIdx.x] = 0.f;
    float sc = g2[cm] * rsqrtf(v2[cm] + EPS_);
    sc2[cm] = sc;
    sh2[cm] = (dwb[cm] - m2[cm]) * sc + b2[cm];
    #pragma unroll
    for (int tap = 0; tap < 9; ++tap) wt[tap * 1024 + cm] = dww[cm * 9 + tap];
}

// ---- generic LN stats reduce: 32 blocks, each folds cnt (sum,sumsq) pairs ----
__global__ void lnreduce_kernel(const float* __restrict__ part, int cnt,
                                float* __restrict__ out) {
    int b = blockIdx.x;
    const float* p = part + (long)b * cnt * 2;
    float s = 0.f, s2 = 0.f;
    for (int i = threadIdx.x; i < cnt; i += 256) {
        s += p[i * 2];
        s2 += p[i * 2 + 1];
    }
    #pragma unroll
    for (int o = 32; o > 0; o >>= 1) {
        s += __shfl_down(s, o);
        s2 += __shfl_down(s2, o);
    }
    __shared__ float ss[4][2];
    int wv = threadIdx.x >> 6;
    if ((threadIdx.x & 63) == 0) { ss[wv][0] = s; ss[wv][1] = s2; }
    __syncthreads();
    if (threadIdx.x == 0) {
        out[b * 2]     = ss[0][0] + ss[1][0] + ss[2][0] + ss[3][0];
        out[b * 2 + 1] = ss[0][1] + ss[1][1] + ss[2][1] + ss[3][1];
    }
}

// ---- LPU: depthwise 3x3 + bias + residual (fp32 channel-major), per-block LN1 partials ----
__global__ void lpu_kernel(const float* __restrict__ x, const float* __restrict__ w,
                           const float* __restrict__ bias, float* __restrict__ out,
                           float* __restrict__ part) {
    int idx = blockIdx.x * blockDim.x + threadIdx.x;
    int p = idx % NPIX;
    int c = (idx / NPIX) % C_;
    int y = p / W_, xx = p % W_;
    const float* xb = x + (size_t)(idx - p);
    const float* wc = w + c * 9;
    float acc = bias[c] + x[idx];
    #pragma unroll
    for (int dy = -1; dy <= 1; ++dy) {
        int yy = y + dy;
        if (yy < 0 || yy >= H_) continue;
        #pragma unroll
        for (int dx = -1; dx <= 1; ++dx) {
            int xc = xx + dx;
            if (xc < 0 || xc >= W_) continue;
            acc += wc[(dy + 1) * 3 + (dx + 1)] * xb[yy * W_ + xc];
        }
    }
    out[idx] = acc;
    float s = acc, s2 = acc * acc;
    #pragma unroll
    for (int o = 32; o > 0; o >>= 1) {
        s += __shfl_down(s, o);
        s2 += __shfl_down(s2, o);
    }
    __shared__ float ss[4][2];
    int wv = threadIdx.x >> 6;
    if ((threadIdx.x & 63) == 0) { ss[wv][0] = s; ss[wv][1] = s2; }
    __syncthreads();
    if (threadIdx.x == 0) {
        part[blockIdx.x * 2]     = ss[0][0] + ss[1][0] + ss[2][0] + ss[3][0];
        part[blockIdx.x * 2 + 1] = ss[0][1] + ss[1][1] + ss[2][1] + ss[3][1];
    }
}

// ---- transpose + LayerNorm: fp32 [b][256][784] -> bf16 [b][784][256] ----
__global__ void tln_kernel(const float* __restrict__ X, const float* __restrict__ st,
                           short* __restrict__ Y) {
    __shared__ float tile[32][33];
    int p0 = blockIdx.x * 32, c0 = blockIdx.y * 32, b = blockIdx.z;
    int tr = threadIdx.x >> 5, tc = threadIdx.x & 31;
    #pragma unroll
    for (int r = 0; r < 4; ++r) {
        int c = c0 + tr + r * 8, p = p0 + tc;
        tile[tr + r * 8][tc] = (p < NPIX) ? X[((long)b * C_ + c) * NPIX + p] : 0.f;
    }
    float sm = st[b * 2] * LN_INVN;
    float lr = rsqrtf(st[b * 2 + 1] * LN_INVN - sm * sm + EPS_);
    __syncthreads();
    #pragma unroll
    for (int r = 0; r < 4; ++r) {
        int p = p0 + tr + r * 8, c = c0 + tc;
        if (p < NPIX) Y[((long)b * NPIX + p) * C_ + c] = f2bf((tile[tc][tr + r * 8] - sm) * lr);
    }
}

// ---- kv depthwise 2x2 stride-2 (x1 fp32 channel-major -> bf16 pixel-major) ----
__global__ void kvconv_kernel(const float* __restrict__ x1, const float* __restrict__ w,
                              const float* __restrict__ bias, short* __restrict__ out) {
    int idx = blockIdx.x * 256 + threadIdx.x;
    if (idx >= B_ * NKPIX * C_) return;
    int c = idx & 255;
    int rest = idx >> 8;
    int p = rest % NKPIX;
    int b = rest / NKPIX;
    int yo = p / HK, xo = p % HK;
    const float* xb = x1 + ((long)b * C_ + c) * NPIX;
    const float* wc = w + c * 4;
    float a = bias[c]
            + wc[0] * xb[(2 * yo) * W_ + 2 * xo]     + wc[1] * xb[(2 * yo) * W_ + 2 * xo + 1]
            + wc[2] * xb[(2 * yo + 1) * W_ + 2 * xo] + wc[3] * xb[(2 * yo + 1) * W_ + 2 * xo + 1];
    out[idx] = f2bf(a);
}

// ---- MFMA GEMM, batch-merged M (rows contiguous across samples), m97-style:
//      global_load_lds width=16 into linear [128][32] LDS tiles, BK=32.
//      M is always an exact multiple of 128 -> no predication anywhere. ----
template <int EPI>
__global__ __launch_bounds__(256) void mfma_gemm(
    const short* __restrict__ Act, const short* __restrict__ Wb,
    int M, int N, int K,
    const float* __restrict__ bias,
    const float* __restrict__ g, const float* __restrict__ bb,
    const float* __restrict__ mm, const float* __restrict__ vv,
    const float* __restrict__ res, float* __restrict__ opart,
    short* __restrict__ outh, float* __restrict__ outf) {
    __shared__ short As[128 * 32];
    __shared__ short Bs[128 * 32];
    const int t = threadIdx.x;
    const int m0 = blockIdx.x * 128;
    const int n0 = blockIdx.y * 128;
    const int w = t >> 6, lane = t & 63;
    const int wm = (w & 1) * 64, wn = (w >> 1) * 64;
    const int col = lane & 15, quad = lane >> 4;

    float4_ acc[4][4];
    #pragma unroll
    for (int i = 0; i < 4; ++i)
        #pragma unroll
        for (int j = 0; j < 4; ++j)
            acc[i][j] = (float4_){0.f, 0.f, 0.f, 0.f};

    // staging: wave w loads A/B rows [w*16, w*16+16) and [w*16+64, w*16+80)
    // lane l supplies row w*16 + l/4, 16B segment l%4 -> LDS linear row*64B + seg*16B
    const int l4 = lane >> 2, seg = lane & 3;
    const short* gA = Act + (long)(m0 + w * 16 + l4) * K + seg * 8;
    const short* gB = Wb  + (long)(n0 + w * 16 + l4) * K + seg * 8;
    const long rs64 = (long)64 * K;
    short* lA = As + w * 512;   // w*16 rows * 32 shorts
    short* lB = Bs + w * 512;

    for (int k0 = 0; k0 < K; k0 += 32) {
        __syncthreads();
        gld16(gA + k0, lA);
        gld16(gA + rs64 + k0, lA + 2048);
        gld16(gB + k0, lB);
        gld16(gB + rs64 + k0, lB + 2048);
        __syncthreads();   // compiler drains vmcnt(0) before this barrier
        short8 af[4], bf[4];
        #pragma unroll
        for (int i = 0; i < 4; ++i)
            af[i] = *(const short8*)(As + (wm + i * 16 + col) * 32 + quad * 8);
        #pragma unroll
        for (int j = 0; j < 4; ++j)
            bf[j] = *(const short8*)(Bs + (wn + j * 16 + col) * 32 + quad * 8);
        #pragma unroll
        for (int i = 0; i < 4; ++i)
            #pragma unroll
            for (int j = 0; j < 4; ++j)
                acc[i][j] = __builtin_amdgcn_mfma_f32_16x16x32_bf16(af[i], bf[j], acc[i][j], 0, 0, 0);
    }

    #pragma unroll
    for (int i = 0; i < 4; ++i) {
        const int pbase = m0 + wm + i * 16 + quad * 4;   // global row (b*784+p)
        float s1 = 0.f, s2s = 0.f;
        int bsmp = 0, psmp = 0;
        if (EPI == 3) { bsmp = pbase / NPIX; psmp = pbase - bsmp * NPIX; }
        #pragma unroll
        for (int j = 0; j < 4; ++j) {
            const int oc = n0 + wn + j * 16 + col;
            if (EPI == 0) {
                float cb = bias[oc];
                #pragma unroll
                for (int r = 0; r < 4; ++r)
                    outh[(long)(pbase + r) * N + oc] = f2bf(acc[i][j][r] + cb);
            } else if (EPI == 1) {
                float sc = g[oc] * rsqrtf(vv[oc] + EPS_);
                float sh = bb[oc] - mm[oc] * sc;
                float cb = bias[oc];
                #pragma unroll
                for (int r = 0; r < 4; ++r)
                    outh[(long)(pbase + r) * N + oc] =
                        f2bf(gelu_f((acc[i][j][r] + cb) * sc + sh));
            } else if (EPI == 2) {
                float cb = bias[oc];
                #pragma unroll
                for (int r = 0; r < 4; ++r) {
                    long jj = (long)(pbase + r) * 256 + oc;
                    float val = acc[i][j][r] + cb + res[jj];
                    outf[jj] = val;
                    s1 += val; s2s += val * val;
                }
            } else {
                float sc = g[oc] * rsqrtf(vv[oc] + EPS_);
                float sh = bb[oc] - mm[oc] * sc;
                float cb = bias[oc];
                long basei = ((long)bsmp * 256 + oc) * NPIX + psmp;
                float4 rv = *(const float4*)(res + basei);
                float4 y;
                y.x = (acc[i][j][0] + cb) * sc + sh + rv.x;
                y.y = (acc[i][j][1] + cb) * sc + sh + rv.y;
                y.z = (acc[i][j][2] + cb) * sc + sh + rv.z;
                y.w = (acc[i][j][3] + cb) * sc + sh + rv.w;
                *(float4*)(outf + basei) = y;
            }
        }
        if (EPI == 2) {
            // each i-group is a 16-aligned 16-row window; 784 % 16 == 0 so the
            // whole wave's rows for this i belong to ONE sample -> full-wave reduce
            #pragma unroll
            for (int o = 32; o > 0; o >>= 1) {
                s1 += __shfl_down(s1, o);
                s2s += __shfl_down(s2s, o);
            }
            if (lane == 0) {
                int bs = pbase / NPIX;
                atomicAdd(&opart[bs * 2], s1);
                atomicAdd(&opart[bs * 2 + 1], s2s);
            }
        }
    }
}

// ---- MFMA flash attention v2: S^T trick ----
__global__ __launch_bounds__(256) void attn_kernel(const short* __restrict__ q,
                                                   const short* __restrict__ k,
                                                   const short* __restrict__ v,
                                                   const float* __restrict__ pos_b,
                                                   short* __restrict__ out) {
    __shared__ short Ks[224 * 40];   // [key][d], rows >=196 zero
    __shared__ short Vt[32 * 248];   // [d][key], cols >=196 zero
    __shared__ short Ps[128 * 72];   // [q][key-in-chunk(64)], per-wave rows
    __shared__ float Ls[128];        // 1/rowsum per q
    const int qt0 = blockIdx.x * 128;
    const int h = blockIdx.y;
    const int b = blockIdx.z;
    const int t = threadIdx.x;
    const short8 z8 = {0, 0, 0, 0, 0, 0, 0, 0};
    for (int e = t; e < 896; e += 256) {
        int row = e >> 2, seg = e & 3;
        short8 v8 = (row < NKPIX)
            ? *(const short8*)(k + ((long)(b * NKPIX + row)) * 256 + h * 32 + seg * 8) : z8;
        *(short8*)(Ks + row * 40 + seg * 8) = v8;
    }
    for (int e = t; e < 784; e += 256) {
        int key = e >> 2, seg = e & 3;
        short8 tv = *(const short8*)(v + ((long)(b * NKPIX + key)) * 256 + h * 32 + seg * 8);
        #pragma unroll
        for (int j = 0; j < 8; ++j) Vt[(seg * 8 + j) * 248 + key] = tv[j];
    }
    for (int e = t; e < 32 * 52; e += 256) {
        Vt[(e / 52) * 248 + 196 + (e % 52)] = 0;
    }
    __syncthreads();

    const int w = t >> 6, lane = t & 63;
    const int col = lane & 15, quad = lane >> 4;
    const float scale = 0.17677669529663689f;
    const float4_ z4 = {0.f, 0.f, 0.f, 0.f};

    short8 bq_[2];
    int qrow[2]; bool qvalid[2];
    #pragma unroll
    for (int i = 0; i < 2; ++i) {
        qrow[i] = qt0 + w * 32 + i * 16 + col;
        qvalid[i] = qrow[i] < NPIX;
        int qe = qvalid[i] ? qrow[i] : 0;
        bq_[i] = *(const short8*)(q + ((long)(b * NPIX + qe)) * 256 + h * 32 + quad * 8);
    }

    float4_ accO[2][2];
    #pragma unroll
    for (int i = 0; i < 2; ++i)
        #pragma unroll
        for (int nt = 0; nt < 2; ++nt) accO[i][nt] = z4;
    float lsum[2] = {0.f, 0.f};

    const int prow0 = w * 32;
    #pragma unroll
    for (int kc = 0; kc < 4; ++kc) {
        const int base = kc * 64;
        const int ntn = (kc == 3) ? 2 : 4;
        for (int nt = 0; nt < ntn; ++nt) {
            short8 afk = *(const short8*)(Ks + (base + nt * 16 + col) * 40 + quad * 8);
            int keybase = base + nt * 16 + quad * 4;
            bool kval = keybase < NKPIX;
            #pragma unroll
            for (int i = 0; i < 2; ++i) {
                float4_ s4 = __builtin_amdgcn_mfma_f32_16x16x32_bf16(afk, bq_[i], z4, 0, 0, 0);
                float4 pv = make_float4(0.f, 0.f, 0.f, 0.f);
                bool valid = kval && qvalid[i];
                if (valid)
                    pv = *(const float4*)(pos_b + ((long)h * NPIX + qrow[i]) * NKPIX + keybase);
                float p0 = valid ? __expf(s4[0] * scale + pv.x) : 0.f;
                float p1 = valid ? __expf(s4[1] * scale + pv.y) : 0.f;
                float p2 = valid ? __expf(s4[2] * scale + pv.z) : 0.f;
                float p3 = valid ? __expf(s4[3] * scale + pv.w) : 0.f;
                lsum[i] += p0 + p1 + p2 + p3;
                short4_ pk = {f2bf(p0), f2bf(p1), f2bf(p2), f2bf(p3)};
                *(short4_*)(Ps + (prow0 + i * 16 + col) * 72 + nt * 16 + quad * 4) = pk;
            }
        }
        const int ksn = (kc == 3) ? 1 : 2;
        for (int ks = 0; ks < ksn; ++ks) {
            #pragma unroll
            for (int i = 0; i < 2; ++i) {
                short8 afp = *(const short8*)(Ps + (prow0 + i * 16 + col) * 72 + ks * 32 + quad * 8);
                #pragma unroll
                for (int nt = 0; nt < 2; ++nt) {
                    short8 bfv = *(const short8*)(Vt + (nt * 16 + col) * 248 + base + ks * 32 + quad * 8);
                    accO[i][nt] = __builtin_amdgcn_mfma_f32_16x16x32_bf16(afp, bfv, accO[i][nt], 0, 0, 0);
                }
            }
        }
    }
    #pragma unroll
    for (int i = 0; i < 2; ++i) {
        float s = lsum[i];
        s += __shfl_xor(s, 16);
        s += __shfl_xor(s, 32);
        if (quad == 0) Ls[prow0 + i * 16 + col] = 1.f / s;
    }
    #pragma unroll
    for (int i = 0; i < 2; ++i) {
        int qb0 = qt0 + prow0 + i * 16 + quad * 4;
        #pragma unroll
        for (int r = 0; r < 4; ++r) {
            int qq = qb0 + r;
            if (qq >= NPIX) continue;
            float rinv = Ls[prow0 + i * 16 + quad * 4 + r];
            #pragma unroll
            for (int nt = 0; nt < 2; ++nt)
                out[((long)(b * NPIX + qq)) * 256 + h * 32 + nt * 16 + col] =
                    f2bf(accO[i][nt][r] * rinv);
        }
    }
}

// ---- dwconv3x3 + BN2 + GELU, 8 channels/thread via short8 ----
__global__ __launch_bounds__(256) void dwgelu_kernel(
    const short* __restrict__ t2, const float* __restrict__ wt,
    const float* __restrict__ sc2, const float* __restrict__ sh2,
    short* __restrict__ t3) {
    int idx = blockIdx.x * 256 + threadIdx.x;  // B*NPIX*128 = 3,211,264
    int cm8 = idx & 127;
    int rest = idx >> 7;
    int p = rest % NPIX;
    int b = rest / NPIX;
    int py = p / W_, px = p % W_;
    int cm0 = cm8 * 8;
    const short* tb = t2 + ((long)b * NPIX) * CM + cm0;
    float acc[8];
    #pragma unroll
    for (int r = 0; r < 8; ++r) acc[r] = 0.f;
    #pragma unroll
    for (int dy = -1; dy <= 1; ++dy) {
        int yy = py + dy;
        if (yy < 0 || yy >= H_) continue;
        #pragma unroll
        for (int dx = -1; dx <= 1; ++dx) {
            int xc = px + dx;
            if (xc < 0 || xc >= W_) continue;
            int tap = (dy + 1) * 3 + (dx + 1);
            short8 tv = *(const short8*)(tb + (long)(yy * W_ + xc) * CM);
            float4 w0 = *(const float4*)(wt + tap * 1024 + cm0);
            float4 w1 = *(const float4*)(wt + tap * 1024 + cm0 + 4);
            acc[0] += bf2f(tv[0]) * w0.x;
            acc[1] += bf2f(tv[1]) * w0.y;
            acc[2] += bf2f(tv[2]) * w0.z;
            acc[3] += bf2f(tv[3]) * w0.w;
            acc[4] += bf2f(tv[4]) * w1.x;
            acc[5] += bf2f(tv[5]) * w1.y;
            acc[6] += bf2f(tv[6]) * w1.z;
            acc[7] += bf2f(tv[7]) * w1.w;
        }
    }
    float4 sa = *(const float4*)(sc2 + cm0);
    float4 sb = *(const float4*)(sc2 + cm0 + 4);
    float4 ha = *(const float4*)(sh2 + cm0);
    float4 hb = *(const float4*)(sh2 + cm0 + 4);
    short8 ov;
    ov[0] = f2bf(gelu_f(acc[0] * sa.x + ha.x));
    ov[1] = f2bf(gelu_f(acc[1] * sa.y + ha.y));
    ov[2] = f2bf(gelu_f(acc[2] * sa.z + ha.z));
    ov[3] = f2bf(gelu_f(acc[3] * sa.w + ha.w));
    ov[4] = f2bf(gelu_f(acc[4] * sb.x + hb.x));
    ov[5] = f2bf(gelu_f(acc[5] * sb.y + hb.y));
    ov[6] = f2bf(gelu_f(acc[6] * sb.z + hb.z));
    ov[7] = f2bf(gelu_f(acc[7] * sb.w + hb.w));
    *(short8*)(t3 + ((long)b * NPIX + p) * CM + cm0) = ov;
}

extern "C" void kernel_launch(void* const* d_in, const int* in_sizes, int n_in,
                              void* d_out, int out_size, void* d_ws, size_t ws_size,
                              hipStream_t stream) {
    const float* x     = (const float*)d_in[0];
    const float* lpu_w = (const float*)d_in[1];
    const float* lpu_b = (const float*)d_in[2];
    const float* dw_w  = (const float*)d_in[3];
    const float* dw_b  = (const float*)d_in[4];
    const float* wq    = (const float*)d_in[5];
    const float* bq    = (const float*)d_in[6];
    const float* wk    = (const float*)d_in[7];
    const float* bk    = (const float*)d_in[8];
    const float* wv    = (const float*)d_in[9];
    const float* bv    = (const float*)d_in[10];
    const float* wo    = (const float*)d_in[11];
    const float* bo    = (const float*)d_in[12];
    const float* posb  = (const float*)d_in[13];
    const float* c1_w  = (const float*)d_in[14];
    const float* c1_b  = (const float*)d_in[15];
    const float* bn1_g = (const float*)d_in[16];
    const float* bn1_b = (const float*)d_in[17];
    const float* bn1_m = (const float*)d_in[18];
    const float* bn1_v = (const float*)d_in[19];
    const float* dw2_w = (const float*)d_in[20];
    const float* dw2_b = (const float*)d_in[21];
    const float* bn2_g = (const float*)d_in[22];
    const float* bn2_b = (const float*)d_in[23];
    const float* bn2_m = (const float*)d_in[24];
    const float* bn2_v = (const float*)d_in[25];
    const float* c2_w  = (const float*)d_in[26];
    const float* c2_b  = (const float*)d_in[27];
    const float* bn3_g = (const float*)d_in[28];
    const float* bn3_b = (const float*)d_in[29];
    const float* bn3_m = (const float*)d_in[30];
    const float* bn3_v = (const float*)d_in[31];

    const long n1  = (long)B_ * C_ * NPIX;    // 6,422,528
    const long nkv = (long)B_ * C_ * NKPIX;   // 1,605,632
    const long nm  = (long)B_ * CM * NPIX;    // 25,690,112
    const int  nblk1 = (int)(n1 / 256);       // 25088 lpu blocks (784 per sample)
    const int  MQ = B_ * NPIX;                // 25088 = 196*128 (exact)
    const int  MKV = B_ * NKPIX;              // 6272  = 49*128  (exact)

    char* base = (char*)d_ws;
    float* x1   = (float*)base; base += n1 * 4;
    float* x2c  = (float*)base; base += n1 * 4;
    short* x1n  = (short*)base; base += n1 * 2;
    short* qb   = (short*)base; base += n1 * 2;
    short* tmpb = (short*)base; base += n1 * 2;
    short* t1n  = (short*)base; base += n1 * 2;
    short* kvb  = (short*)base; base += nkv * 2;
    short* kb   = (short*)base; base += nkv * 2;
    short* vb   = (short*)base; base += nkv * 2;
    short* t2   = (short*)base; base += nm * 2;
    short* t3   = (short*)base; base += nm * 2;
    short* wbf  = (short*)base; base += 786432L * 2;
    float* stats = (float*)base; base += 128 * 4;
    float* dwt   = (float*)base; base += 9216 * 4;   // [9][1024]
    float* dsc   = (float*)base; base += 1024 * 4;
    float* dsh   = (float*)base; base += 1024 * 4;
    float* part1 = (float*)base; base += (long)nblk1 * 2 * 4;
    float* outp = (float*)d_out;

    wconv_kernel<<<3072, 256, 0, stream>>>(wq, wk, wv, wo, c1_w, c2_w, wbf);
    dwprep_kernel<<<4, 256, 0, stream>>>(dw2_w, dw2_b, bn2_g, bn2_b, bn2_m, bn2_v,
                                         dwt, dsc, dsh, stats + 64);
    lpu_kernel<<<nblk1, 256, 0, stream>>>(x, lpu_w, lpu_b, x1, part1);
    lnreduce_kernel<<<B_, 256, 0, stream>>>(part1, nblk1 / B_, stats);
    kvconv_kernel<<<(int)((nkv + 255) / 256), 256, 0, stream>>>(x1, dw_w, dw_b, kvb);
    tln_kernel<<<dim3(25, 8, B_), 256, 0, stream>>>(x1, stats, x1n);
    // q/k/v projections (batch-merged M)
    mfma_gemm<0><<<dim3(MQ / 128, 2), 256, 0, stream>>>(
        x1n, wbf, MQ, 256, 256, bq, nullptr, nullptr, nullptr, nullptr,
        nullptr, nullptr, qb, nullptr);
    mfma_gemm<0><<<dim3(MKV / 128, 2), 256, 0, stream>>>(
        kvb, wbf + 65536, MKV, 256, 256, bk, nullptr, nullptr, nullptr, nullptr,
        nullptr, nullptr, kb, nullptr);
    mfma_gemm<0><<<dim3(MKV / 128, 2), 256, 0, stream>>>(
        kvb, wbf + 131072, MKV, 256, 256, bv, nullptr, nullptr, nullptr, nullptr,
        nullptr, nullptr, vb, nullptr);
    attn_kernel<<<dim3(7, 8, B_), 256, 0, stream>>>(qb, kb, vb, posb, tmpb);
    // wo + flat residual + LN2 stats via atomics into stats+64 (zeroed in dwprep)
    mfma_gemm<2><<<dim3(MQ / 128, 2), 256, 0, stream>>>(
        tmpb, wbf + 196608, MQ, 256, 256, bo, nullptr, nullptr, nullptr, nullptr,
        x1, stats + 64, nullptr, x2c);
    tln_kernel<<<dim3(25, 8, B_), 256, 0, stream>>>(x2c, stats + 64, t1n);
    // conv1 1x1 + BN1 + GELU
    mfma_gemm<1><<<dim3(MQ / 128, 8), 256, 0, stream>>>(
        t1n, wbf + 262144, MQ, CM, 256, c1_b, bn1_g, bn1_b, bn1_m, bn1_v,
        nullptr, nullptr, t2, nullptr);
    dwgelu_kernel<<<(int)(B_ * NPIX * 128 / 256), 256, 0, stream>>>(t2, dwt, dsc, dsh, t3);
    // conv2 1x1 + BN3 + residual -> d_out (channel-major)
    mfma_gemm<3><<<dim3(MQ / 128, 2), 256, 0, stream>>>(
        t3, wbf + 524288, MQ, 256, 1024, c2_b, bn3_g, bn3_b, bn3_m, bn3_v,
        x2c, nullptr, nullptr, outp);
}

// Round 3
// 478.005 us; speedup vs baseline: 1.1503x; 1.1503x over previous
//
#include <hip/hip_runtime.h>
#include <math.h>

#define B_ 32
#define C_ 256
#define H_ 28
#define W_ 28
#define NPIX 784
#define HK 14
#define NKPIX 196
#define CM 1024
#define EPS_ 1e-5f
#define LN_INVN (1.0f / (C_ * NPIX))

typedef __attribute__((ext_vector_type(8))) short short8;
typedef __attribute__((ext_vector_type(4))) short short4_;
typedef __attribute__((ext_vector_type(4))) float float4_;

__device__ __forceinline__ float gelu_f(float x) {
    return 0.5f * x * (1.0f + erff(x * 0.70710678118654752f));
}
__device__ __forceinline__ short f2bf(float f) {
    union { float f; unsigned u; } x; x.f = f;
    unsigned r = x.u + 0x7FFF + ((x.u >> 16) & 1);
    return (short)(r >> 16);
}
__device__ __forceinline__ float bf2f(short s) {
    union { unsigned u; float f; } x; x.u = ((unsigned)(unsigned short)s) << 16;
    return x.f;
}
// async global->LDS, 16B per lane; LDS dest is wave-uniform base + lane*16
__device__ __forceinline__ void gld16(const short* g, short* l) {
    __builtin_amdgcn_global_load_lds((const __attribute__((address_space(1))) void*)g,
                                     (__attribute__((address_space(3))) void*)l,
                                     16, 0, 0);
}

// ---- convert all 6 weight matrices to bf16 (layout [oc][k], k contiguous) ----
__global__ void wconv_kernel(const float* __restrict__ wq, const float* __restrict__ wk,
                             const float* __restrict__ wv, const float* __restrict__ wo,
                             const float* __restrict__ c1, const float* __restrict__ c2,
                             short* __restrict__ dst) {
    int idx = blockIdx.x * 256 + threadIdx.x;  // total 786432
    const float* src; int off;
    if (idx < 65536)       { src = wq; off = idx; }
    else if (idx < 131072) { src = wk; off = idx - 65536; }
    else if (idx < 196608) { src = wv; off = idx - 131072; }
    else if (idx < 262144) { src = wo; off = idx - 196608; }
    else if (idx < 524288) { src = c1; off = idx - 262144; }
    else                   { src = c2; off = idx - 524288; }
    dst[idx] = f2bf(src[off]);
}

// ---- prep for dwgelu: transpose dww to [tap][1024], fold dwb+BN2 to (sc,sh);
//      also zero the LN2 atomic-stat accumulator (runs before all GEMMs) ----
__global__ void dwprep_kernel(const float* __restrict__ dww, const float* __restrict__ dwb,
                              const float* __restrict__ g2, const float* __restrict__ b2,
                              const float* __restrict__ m2, const float* __restrict__ v2,
                              float* __restrict__ wt, float* __restrict__ sc2,
                              float* __restrict__ sh2, float* __restrict__ st2) {
    int cm = blockIdx.x * 256 + threadIdx.x;  // 1024
    if (blockIdx.x == 0 && threadIdx.x < 64) st2[threadIdx.x] = 0.f;
    float sc = g2[cm] * rsqrtf(v2[cm] + EPS_);
    sc2[cm] = sc;
    sh2[cm] = (dwb[cm] - m2[cm]) * sc + b2[cm];
    #pragma unroll
    for (int tap = 0; tap < 9; ++tap) wt[tap * 1024 + cm] = dww[cm * 9 + tap];
}

// ---- generic LN stats reduce: 32 blocks, each folds cnt (sum,sumsq) pairs ----
__global__ void lnreduce_kernel(const float* __restrict__ part, int cnt,
                                float* __restrict__ out) {
    int b = blockIdx.x;
    const float* p = part + (long)b * cnt * 2;
    float s = 0.f, s2 = 0.f;
    for (int i = threadIdx.x; i < cnt; i += 256) {
        s += p[i * 2];
        s2 += p[i * 2 + 1];
    }
    #pragma unroll
    for (int o = 32; o > 0; o >>= 1) {
        s += __shfl_down(s, o);
        s2 += __shfl_down(s2, o);
    }
    __shared__ float ss[4][2];
    int wv = threadIdx.x >> 6;
    if ((threadIdx.x & 63) == 0) { ss[wv][0] = s; ss[wv][1] = s2; }
    __syncthreads();
    if (threadIdx.x == 0) {
        out[b * 2]     = ss[0][0] + ss[1][0] + ss[2][0] + ss[3][0];
        out[b * 2 + 1] = ss[0][1] + ss[1][1] + ss[2][1] + ss[3][1];
    }
}

// ---- LPU: depthwise 3x3 + bias + residual (fp32 channel-major), per-block LN1 partials ----
__global__ void lpu_kernel(const float* __restrict__ x, const float* __restrict__ w,
                           const float* __restrict__ bias, float* __restrict__ out,
                           float* __restrict__ part) {
    int idx = blockIdx.x * blockDim.x + threadIdx.x;
    int p = idx % NPIX;
    int c = (idx / NPIX) % C_;
    int y = p / W_, xx = p % W_;
    const float* xb = x + (size_t)(idx - p);
    const float* wc = w + c * 9;
    float acc = bias[c] + x[idx];
    #pragma unroll
    for (int dy = -1; dy <= 1; ++dy) {
        int yy = y + dy;
        if (yy < 0 || yy >= H_) continue;
        #pragma unroll
        for (int dx = -1; dx <= 1; ++dx) {
            int xc = xx + dx;
            if (xc < 0 || xc >= W_) continue;
            acc += wc[(dy + 1) * 3 + (dx + 1)] * xb[yy * W_ + xc];
        }
    }
    out[idx] = acc;
    float s = acc, s2 = acc * acc;
    #pragma unroll
    for (int o = 32; o > 0; o >>= 1) {
        s += __shfl_down(s, o);
        s2 += __shfl_down(s2, o);
    }
    __shared__ float ss[4][2];
    int wv = threadIdx.x >> 6;
    if ((threadIdx.x & 63) == 0) { ss[wv][0] = s; ss[wv][1] = s2; }
    __syncthreads();
    if (threadIdx.x == 0) {
        part[blockIdx.x * 2]     = ss[0][0] + ss[1][0] + ss[2][0] + ss[3][0];
        part[blockIdx.x * 2 + 1] = ss[0][1] + ss[1][1] + ss[2][1] + ss[3][1];
    }
}

// ---- transpose + LayerNorm: fp32 [b][256][784] -> bf16 [b][784][256] ----
__global__ void tln_kernel(const float* __restrict__ X, const float* __restrict__ st,
                           short* __restrict__ Y) {
    __shared__ float tile[32][33];
    int p0 = blockIdx.x * 32, c0 = blockIdx.y * 32, b = blockIdx.z;
    int tr = threadIdx.x >> 5, tc = threadIdx.x & 31;
    #pragma unroll
    for (int r = 0; r < 4; ++r) {
        int c = c0 + tr + r * 8, p = p0 + tc;
        tile[tr + r * 8][tc] = (p < NPIX) ? X[((long)b * C_ + c) * NPIX + p] : 0.f;
    }
    float sm = st[b * 2] * LN_INVN;
    float lr = rsqrtf(st[b * 2 + 1] * LN_INVN - sm * sm + EPS_);
    __syncthreads();
    #pragma unroll
    for (int r = 0; r < 4; ++r) {
        int p = p0 + tr + r * 8, c = c0 + tc;
        if (p < NPIX) Y[((long)b * NPIX + p) * C_ + c] = f2bf((tile[tc][tr + r * 8] - sm) * lr);
    }
}

// ---- kv depthwise 2x2 stride-2 (x1 fp32 channel-major -> bf16 pixel-major) ----
__global__ void kvconv_kernel(const float* __restrict__ x1, const float* __restrict__ w,
                              const float* __restrict__ bias, short* __restrict__ out) {
    int idx = blockIdx.x * 256 + threadIdx.x;
    if (idx >= B_ * NKPIX * C_) return;
    int c = idx & 255;
    int rest = idx >> 8;
    int p = rest % NKPIX;
    int b = rest / NKPIX;
    int yo = p / HK, xo = p % HK;
    const float* xb = x1 + ((long)b * C_ + c) * NPIX;
    const float* wc = w + c * 4;
    float a = bias[c]
            + wc[0] * xb[(2 * yo) * W_ + 2 * xo]     + wc[1] * xb[(2 * yo) * W_ + 2 * xo + 1]
            + wc[2] * xb[(2 * yo + 1) * W_ + 2 * xo] + wc[3] * xb[(2 * yo + 1) * W_ + 2 * xo + 1];
    out[idx] = f2bf(a);
}

// ---- MFMA GEMM, batch-merged M, 2-phase double-buffered global_load_lds:
//      issue next K-tile's loads BEFORE computing current tile; ONE barrier
//      per K-step (compiler's vmcnt(0)-before-barrier lands after compute).
//      16B-slot XOR swizzle via pre-swizzled global source -> 2-way (free)
//      ds_read_b128 bank pattern. M always a multiple of 128: no predication. ----
template <int EPI>
__global__ __launch_bounds__(256) void mfma_gemm(
    const short* __restrict__ Act, const short* __restrict__ Wb,
    int M, int N, int K,
    const float* __restrict__ bias,
    const float* __restrict__ g, const float* __restrict__ bb,
    const float* __restrict__ mm, const float* __restrict__ vv,
    const float* __restrict__ res, float* __restrict__ opart,
    short* __restrict__ outh, float* __restrict__ outf) {
    __shared__ short As[2 * 128 * 32];
    __shared__ short Bs[2 * 128 * 32];
    __shared__ float red[16][3];
    const int t = threadIdx.x;
    const int m0 = blockIdx.x * 128;
    const int n0 = blockIdx.y * 128;
    const int w = t >> 6, lane = t & 63;
    const int wm = (w & 1) * 64, wn = (w >> 1) * 64;
    const int col = lane & 15, quad = lane >> 4;

    float4_ acc[4][4];
    #pragma unroll
    for (int i = 0; i < 4; ++i)
        #pragma unroll
        for (int j = 0; j < 4; ++j)
            acc[i][j] = (float4_){0.f, 0.f, 0.f, 0.f};

    // staging: wave w loads rows [w*16,+16) and [w*16+64,+16) of A and B.
    // lane l -> row = chunkbase + l/4, 16B slot (l&3); global source slot is
    // XOR-swizzled by f(row) = (row ^ (row>>2)) & 3, which for chunkbase%16==0
    // reduces to a lane-constant: f = ((l>>2) ^ (l>>4)) & 3.
    const int l4 = lane >> 2;
    const int segsw = (lane & 3) ^ ((l4 ^ (l4 >> 2)) & 3);
    const short* gA = Act + (long)(m0 + w * 16 + l4) * K + segsw * 8;
    const short* gB = Wb  + (long)(n0 + w * 16 + l4) * K + segsw * 8;
    const long rs64 = (long)64 * K;
    const int woff = w * 512;   // w*16 rows * 32 shorts

    const int nk = K >> 5;
    // prologue: stage K-tile 0 into buffer 0
    {
        short* dA = As + woff;
        short* dB = Bs + woff;
        gld16(gA, dA);
        gld16(gA + rs64, dA + 2048);
        gld16(gB, dB);
        gld16(gB + rs64, dB + 2048);
    }
    // frag read slot: quad XOR-ed with f(row); row = wm|wn + i*16 + col makes
    // f = ((col&3) ^ ((col>>2)&3)) -- lane-constant.
    const int slotsw = (quad ^ ((col & 3) ^ ((col >> 2) & 3))) * 8;

    for (int kt = 0; kt < nk; ++kt) {
        __syncthreads();   // buf[kt&1] staged (vmcnt drained); prev reads done
        const int cur = (kt & 1) * 4096;
        if (kt + 1 < nk) {
            const int nxtoff = ((kt + 1) & 1) * 4096 + woff;
            const int k0 = (kt + 1) * 32;
            gld16(gA + k0, As + nxtoff);
            gld16(gA + rs64 + k0, As + nxtoff + 2048);
            gld16(gB + k0, Bs + nxtoff);
            gld16(gB + rs64 + k0, Bs + nxtoff + 2048);
        }
        short8 af[4], bf[4];
        #pragma unroll
        for (int i = 0; i < 4; ++i)
            af[i] = *(const short8*)(As + cur + (wm + i * 16 + col) * 32 + slotsw);
        #pragma unroll
        for (int j = 0; j < 4; ++j)
            bf[j] = *(const short8*)(Bs + cur + (wn + j * 16 + col) * 32 + slotsw);
        #pragma unroll
        for (int i = 0; i < 4; ++i)
            #pragma unroll
            for (int j = 0; j < 4; ++j)
                acc[i][j] = __builtin_amdgcn_mfma_f32_16x16x32_bf16(af[i], bf[j], acc[i][j], 0, 0, 0);
    }

    #pragma unroll
    for (int i = 0; i < 4; ++i) {
        const int pbase = m0 + wm + i * 16 + quad * 4;   // global row (b*784+p)
        float s1 = 0.f, s2s = 0.f;
        int bsmp = 0, psmp = 0;
        if (EPI == 3) { bsmp = pbase / NPIX; psmp = pbase - bsmp * NPIX; }
        #pragma unroll
        for (int j = 0; j < 4; ++j) {
            const int oc = n0 + wn + j * 16 + col;
            if (EPI == 0) {
                float cb = bias[oc];
                #pragma unroll
                for (int r = 0; r < 4; ++r)
                    outh[(long)(pbase + r) * N + oc] = f2bf(acc[i][j][r] + cb);
            } else if (EPI == 1) {
                float sc = g[oc] * rsqrtf(vv[oc] + EPS_);
                float sh = bb[oc] - mm[oc] * sc;
                float cb = bias[oc];
                #pragma unroll
                for (int r = 0; r < 4; ++r)
                    outh[(long)(pbase + r) * N + oc] =
                        f2bf(gelu_f((acc[i][j][r] + cb) * sc + sh));
            } else if (EPI == 2) {
                float cb = bias[oc];
                #pragma unroll
                for (int r = 0; r < 4; ++r) {
                    long jj = (long)(pbase + r) * 256 + oc;
                    float val = acc[i][j][r] + cb + res[jj];
                    outf[jj] = val;
                    s1 += val; s2s += val * val;
                }
            } else {
                float sc = g[oc] * rsqrtf(vv[oc] + EPS_);
                float sh = bb[oc] - mm[oc] * sc;
                float cb = bias[oc];
                long basei = ((long)bsmp * 256 + oc) * NPIX + psmp;
                float4 rv = *(const float4*)(res + basei);
                float4 y;
                y.x = (acc[i][j][0] + cb) * sc + sh + rv.x;
                y.y = (acc[i][j][1] + cb) * sc + sh + rv.y;
                y.z = (acc[i][j][2] + cb) * sc + sh + rv.z;
                y.w = (acc[i][j][3] + cb) * sc + sh + rv.w;
                *(float4*)(outf + basei) = y;
            }
        }
        if (EPI == 2) {
            // 16-row groups never straddle a sample (784 % 16 == 0):
            // full-wave reduce, then stash per-group sums for a block-level fold
            #pragma unroll
            for (int o = 32; o > 0; o >>= 1) {
                s1 += __shfl_down(s1, o);
                s2s += __shfl_down(s2s, o);
            }
            if (lane == 0) {
                red[w * 4 + i][0] = (float)(pbase / NPIX);
                red[w * 4 + i][1] = s1;
                red[w * 4 + i][2] = s2s;
            }
        }
    }
    if (EPI == 2) {
        // a 128-row tile touches at most 2 samples -> <=2 atomic pairs per block
        __syncthreads();
        if (t == 0) {
            int bsA = (int)red[0][0], bsB = -1;
            float a1 = 0.f, a2 = 0.f, b1 = 0.f, b2 = 0.f;
            #pragma unroll
            for (int e = 0; e < 16; ++e) {
                int bs = (int)red[e][0];
                if (bs == bsA) { a1 += red[e][1]; a2 += red[e][2]; }
                else           { bsB = bs; b1 += red[e][1]; b2 += red[e][2]; }
            }
            atomicAdd(&opart[bsA * 2], a1);
            atomicAdd(&opart[bsA * 2 + 1], a2);
            if (bsB >= 0) {
                atomicAdd(&opart[bsB * 2], b1);
                atomicAdd(&opart[bsB * 2 + 1], b2);
            }
        }
    }
}

// ---- MFMA flash attention v2: S^T trick ----
__global__ __launch_bounds__(256) void attn_kernel(const short* __restrict__ q,
                                                   const short* __restrict__ k,
                                                   const short* __restrict__ v,
                                                   const float* __restrict__ pos_b,
                                                   short* __restrict__ out) {
    __shared__ short Ks[224 * 40];   // [key][d], rows >=196 zero
    __shared__ short Vt[32 * 248];   // [d][key], cols >=196 zero
    __shared__ short Ps[128 * 72];   // [q][key-in-chunk(64)], per-wave rows
    __shared__ float Ls[128];        // 1/rowsum per q
    const int qt0 = blockIdx.x * 128;
    const int h = blockIdx.y;
    const int b = blockIdx.z;
    const int t = threadIdx.x;
    const short8 z8 = {0, 0, 0, 0, 0, 0, 0, 0};
    for (int e = t; e < 896; e += 256) {
        int row = e >> 2, seg = e & 3;
        short8 v8 = (row < NKPIX)
            ? *(const short8*)(k + ((long)(b * NKPIX + row)) * 256 + h * 32 + seg * 8) : z8;
        *(short8*)(Ks + row * 40 + seg * 8) = v8;
    }
    for (int e = t; e < 784; e += 256) {
        int key = e >> 2, seg = e & 3;
        short8 tv = *(const short8*)(v + ((long)(b * NKPIX + key)) * 256 + h * 32 + seg * 8);
        #pragma unroll
        for (int j = 0; j < 8; ++j) Vt[(seg * 8 + j) * 248 + key] = tv[j];
    }
    for (int e = t; e < 32 * 52; e += 256) {
        Vt[(e / 52) * 248 + 196 + (e % 52)] = 0;
    }
    __syncthreads();

    const int w = t >> 6, lane = t & 63;
    const int col = lane & 15, quad = lane >> 4;
    const float scale = 0.17677669529663689f;
    const float4_ z4 = {0.f, 0.f, 0.f, 0.f};

    short8 bq_[2];
    int qrow[2]; bool qvalid[2];
    #pragma unroll
    for (int i = 0; i < 2; ++i) {
        qrow[i] = qt0 + w * 32 + i * 16 + col;
        qvalid[i] = qrow[i] < NPIX;
        int qe = qvalid[i] ? qrow[i] : 0;
        bq_[i] = *(const short8*)(q + ((long)(b * NPIX + qe)) * 256 + h * 32 + quad * 8);
    }

    float4_ accO[2][2];
    #pragma unroll
    for (int i = 0; i < 2; ++i)
        #pragma unroll
        for (int nt = 0; nt < 2; ++nt) accO[i][nt] = z4;
    float lsum[2] = {0.f, 0.f};

    const int prow0 = w * 32;
    #pragma unroll
    for (int kc = 0; kc < 4; ++kc) {
        const int base = kc * 64;
        const int ntn = (kc == 3) ? 2 : 4;
        for (int nt = 0; nt < ntn; ++nt) {
            short8 afk = *(const short8*)(Ks + (base + nt * 16 + col) * 40 + quad * 8);
            int keybase = base + nt * 16 + quad * 4;
            bool kval = keybase < NKPIX;
            #pragma unroll
            for (int i = 0; i < 2; ++i) {
                float4_ s4 = __builtin_amdgcn_mfma_f32_16x16x32_bf16(afk, bq_[i], z4, 0, 0, 0);
                float4 pv = make_float4(0.f, 0.f, 0.f, 0.f);
                bool valid = kval && qvalid[i];
                if (valid)
                    pv = *(const float4*)(pos_b + ((long)h * NPIX + qrow[i]) * NKPIX + keybase);
                float p0 = valid ? __expf(s4[0] * scale + pv.x) : 0.f;
                float p1 = valid ? __expf(s4[1] * scale + pv.y) : 0.f;
                float p2 = valid ? __expf(s4[2] * scale + pv.z) : 0.f;
                float p3 = valid ? __expf(s4[3] * scale + pv.w) : 0.f;
                lsum[i] += p0 + p1 + p2 + p3;
                short4_ pk = {f2bf(p0), f2bf(p1), f2bf(p2), f2bf(p3)};
                *(short4_*)(Ps + (prow0 + i * 16 + col) * 72 + nt * 16 + quad * 4) = pk;
            }
        }
        const int ksn = (kc == 3) ? 1 : 2;
        for (int ks = 0; ks < ksn; ++ks) {
            #pragma unroll
            for (int i = 0; i < 2; ++i) {
                short8 afp = *(const short8*)(Ps + (prow0 + i * 16 + col) * 72 + ks * 32 + quad * 8);
                #pragma unroll
                for (int nt = 0; nt < 2; ++nt) {
                    short8 bfv = *(const short8*)(Vt + (nt * 16 + col) * 248 + base + ks * 32 + quad * 8);
                    accO[i][nt] = __builtin_amdgcn_mfma_f32_16x16x32_bf16(afp, bfv, accO[i][nt], 0, 0, 0);
                }
            }
        }
    }
    #pragma unroll
    for (int i = 0; i < 2; ++i) {
        float s = lsum[i];
        s += __shfl_xor(s, 16);
        s += __shfl_xor(s, 32);
        if (quad == 0) Ls[prow0 + i * 16 + col] = 1.f / s;
    }
    #pragma unroll
    for (int i = 0; i < 2; ++i) {
        int qb0 = qt0 + prow0 + i * 16 + quad * 4;
        #pragma unroll
        for (int r = 0; r < 4; ++r) {
            int qq = qb0 + r;
            if (qq >= NPIX) continue;
            float rinv = Ls[prow0 + i * 16 + quad * 4 + r];
            #pragma unroll
            for (int nt = 0; nt < 2; ++nt)
                out[((long)(b * NPIX + qq)) * 256 + h * 32 + nt * 16 + col] =
                    f2bf(accO[i][nt][r] * rinv);
        }
    }
}

// ---- dwconv3x3 + BN2 + GELU, 8 channels/thread via short8 ----
__global__ __launch_bounds__(256) void dwgelu_kernel(
    const short* __restrict__ t2, const float* __restrict__ wt,
    const float* __restrict__ sc2, const float* __restrict__ sh2,
    short* __restrict__ t3) {
    int idx = blockIdx.x * 256 + threadIdx.x;  // B*NPIX*128 = 3,211,264
    int cm8 = idx & 127;
    int rest = idx >> 7;
    int p = rest % NPIX;
    int b = rest / NPIX;
    int py = p / W_, px = p % W_;
    int cm0 = cm8 * 8;
    const short* tb = t2 + ((long)b * NPIX) * CM + cm0;
    float acc[8];
    #pragma unroll
    for (int r = 0; r < 8; ++r) acc[r] = 0.f;
    #pragma unroll
    for (int dy = -1; dy <= 1; ++dy) {
        int yy = py + dy;
        if (yy < 0 || yy >= H_) continue;
        #pragma unroll
        for (int dx = -1; dx <= 1; ++dx) {
            int xc = px + dx;
            if (xc < 0 || xc >= W_) continue;
            int tap = (dy + 1) * 3 + (dx + 1);
            short8 tv = *(const short8*)(tb + (long)(yy * W_ + xc) * CM);
            float4 w0 = *(const float4*)(wt + tap * 1024 + cm0);
            float4 w1 = *(const float4*)(wt + tap * 1024 + cm0 + 4);
            acc[0] += bf2f(tv[0]) * w0.x;
            acc[1] += bf2f(tv[1]) * w0.y;
            acc[2] += bf2f(tv[2]) * w0.z;
            acc[3] += bf2f(tv[3]) * w0.w;
            acc[4] += bf2f(tv[4]) * w1.x;
            acc[5] += bf2f(tv[5]) * w1.y;
            acc[6] += bf2f(tv[6]) * w1.z;
            acc[7] += bf2f(tv[7]) * w1.w;
        }
    }
    float4 sa = *(const float4*)(sc2 + cm0);
    float4 sb = *(const float4*)(sc2 + cm0 + 4);
    float4 ha = *(const float4*)(sh2 + cm0);
    float4 hb = *(const float4*)(sh2 + cm0 + 4);
    short8 ov;
    ov[0] = f2bf(gelu_f(acc[0] * sa.x + ha.x));
    ov[1] = f2bf(gelu_f(acc[1] * sa.y + ha.y));
    ov[2] = f2bf(gelu_f(acc[2] * sa.z + ha.z));
    ov[3] = f2bf(gelu_f(acc[3] * sa.w + ha.w));
    ov[4] = f2bf(gelu_f(acc[4] * sb.x + hb.x));
    ov[5] = f2bf(gelu_f(acc[5] * sb.y + hb.y));
    ov[6] = f2bf(gelu_f(acc[6] * sb.z + hb.z));
    ov[7] = f2bf(gelu_f(acc[7] * sb.w + hb.w));
    *(short8*)(t3 + ((long)b * NPIX + p) * CM + cm0) = ov;
}

extern "C" void kernel_launch(void* const* d_in, const int* in_sizes, int n_in,
                              void* d_out, int out_size, void* d_ws, size_t ws_size,
                              hipStream_t stream) {
    const float* x     = (const float*)d_in[0];
    const float* lpu_w = (const float*)d_in[1];
    const float* lpu_b = (const float*)d_in[2];
    const float* dw_w  = (const float*)d_in[3];
    const float* dw_b  = (const float*)d_in[4];
    const float* wq    = (const float*)d_in[5];
    const float* bq    = (const float*)d_in[6];
    const float* wk    = (const float*)d_in[7];
    const float* bk    = (const float*)d_in[8];
    const float* wv    = (const float*)d_in[9];
    const float* bv    = (const float*)d_in[10];
    const float* wo    = (const float*)d_in[11];
    const float* bo    = (const float*)d_in[12];
    const float* posb  = (const float*)d_in[13];
    const float* c1_w  = (const float*)d_in[14];
    const float* c1_b  = (const float*)d_in[15];
    const float* bn1_g = (const float*)d_in[16];
    const float* bn1_b = (const float*)d_in[17];
    const float* bn1_m = (const float*)d_in[18];
    const float* bn1_v = (const float*)d_in[19];
    const float* dw2_w = (const float*)d_in[20];
    const float* dw2_b = (const float*)d_in[21];
    const float* bn2_g = (const float*)d_in[22];
    const float* bn2_b = (const float*)d_in[23];
    const float* bn2_m = (const float*)d_in[24];
    const float* bn2_v = (const float*)d_in[25];
    const float* c2_w  = (const float*)d_in[26];
    const float* c2_b  = (const float*)d_in[27];
    const float* bn3_g = (const float*)d_in[28];
    const float* bn3_b = (const float*)d_in[29];
    const float* bn3_m = (const float*)d_in[30];
    const float* bn3_v = (const float*)d_in[31];

    const long n1  = (long)B_ * C_ * NPIX;    // 6,422,528
    const long nkv = (long)B_ * C_ * NKPIX;   // 1,605,632
    const long nm  = (long)B_ * CM * NPIX;    // 25,690,112
    const int  nblk1 = (int)(n1 / 256);       // 25088 lpu blocks (784 per sample)
    const int  MQ = B_ * NPIX;                // 25088 = 196*128 (exact)
    const int  MKV = B_ * NKPIX;              // 6272  = 49*128  (exact)

    char* base = (char*)d_ws;
    float* x1   = (float*)base; base += n1 * 4;
    float* x2c  = (float*)base; base += n1 * 4;
    short* x1n  = (short*)base; base += n1 * 2;
    short* qb   = (short*)base; base += n1 * 2;
    short* tmpb = (short*)base; base += n1 * 2;
    short* t1n  = (short*)base; base += n1 * 2;
    short* kvb  = (short*)base; base += nkv * 2;
    short* kb   = (short*)base; base += nkv * 2;
    short* vb   = (short*)base; base += nkv * 2;
    short* t2   = (short*)base; base += nm * 2;
    short* t3   = (short*)base; base += nm * 2;
    short* wbf  = (short*)base; base += 786432L * 2;
    float* stats = (float*)base; base += 128 * 4;
    float* dwt   = (float*)base; base += 9216 * 4;   // [9][1024]
    float* dsc   = (float*)base; base += 1024 * 4;
    float* dsh   = (float*)base; base += 1024 * 4;
    float* part1 = (float*)base; base += (long)nblk1 * 2 * 4;
    float* outp = (float*)d_out;

    wconv_kernel<<<3072, 256, 0, stream>>>(wq, wk, wv, wo, c1_w, c2_w, wbf);
    dwprep_kernel<<<4, 256, 0, stream>>>(dw2_w, dw2_b, bn2_g, bn2_b, bn2_m, bn2_v,
                                         dwt, dsc, dsh, stats + 64);
    lpu_kernel<<<nblk1, 256, 0, stream>>>(x, lpu_w, lpu_b, x1, part1);
    lnreduce_kernel<<<B_, 256, 0, stream>>>(part1, nblk1 / B_, stats);
    kvconv_kernel<<<(int)((nkv + 255) / 256), 256, 0, stream>>>(x1, dw_w, dw_b, kvb);
    tln_kernel<<<dim3(25, 8, B_), 256, 0, stream>>>(x1, stats, x1n);
    // q/k/v projections (batch-merged M)
    mfma_gemm<0><<<dim3(MQ / 128, 2), 256, 0, stream>>>(
        x1n, wbf, MQ, 256, 256, bq, nullptr, nullptr, nullptr, nullptr,
        nullptr, nullptr, qb, nullptr);
    mfma_gemm<0><<<dim3(MKV / 128, 2), 256, 0, stream>>>(
        kvb, wbf + 65536, MKV, 256, 256, bk, nullptr, nullptr, nullptr, nullptr,
        nullptr, nullptr, kb, nullptr);
    mfma_gemm<0><<<dim3(MKV / 128, 2), 256, 0, stream>>>(
        kvb, wbf + 131072, MKV, 256, 256, bv, nullptr, nullptr, nullptr, nullptr,
        nullptr, nullptr, vb, nullptr);
    attn_kernel<<<dim3(7, 8, B_), 256, 0, stream>>>(qb, kb, vb, posb, tmpb);
    // wo + flat residual + LN2 stats via per-block-reduced atomics into stats+64
    mfma_gemm<2><<<dim3(MQ / 128, 2), 256, 0, stream>>>(
        tmpb, wbf + 196608, MQ, 256, 256, bo, nullptr, nullptr, nullptr, nullptr,
        x1, stats + 64, nullptr, x2c);
    tln_kernel<<<dim3(25, 8, B_), 256, 0, stream>>>(x2c, stats + 64, t1n);
    // conv1 1x1 + BN1 + GELU
    mfma_gemm<1><<<dim3(MQ / 128, 8), 256, 0, stream>>>(
        t1n, wbf + 262144, MQ, CM, 256, c1_b, bn1_g, bn1_b, bn1_m, bn1_v,
        nullptr, nullptr, t2, nullptr);
    dwgelu_kernel<<<(int)(B_ * NPIX * 128 / 256), 256, 0, stream>>>(t2, dwt, dsc, dsh, t3);
    // conv2 1x1 + BN3 + residual -> d_out (channel-major)
    mfma_gemm<3><<<dim3(MQ / 128, 2), 256, 0, stream>>>(
        t3, wbf + 524288, MQ, 256, 1024, c2_b, bn3_g, bn3_b, bn3_m, bn3_v,
        x2c, nullptr, nullptr, outp);
}

// Round 4
// 470.644 us; speedup vs baseline: 1.1683x; 1.0156x over previous
//
#include <hip/hip_runtime.h>
#include <math.h>

#define B_ 32
#define C_ 256
#define H_ 28
#define W_ 28
#define NPIX 784
#define HK 14
#define NKPIX 196
#define CM 1024
#define EPS_ 1e-5f
#define LN_INVN (1.0f / (C_ * NPIX))

typedef __attribute__((ext_vector_type(8))) short short8;
typedef __attribute__((ext_vector_type(4))) short short4_;
typedef __attribute__((ext_vector_type(4))) float float4_;

__device__ __forceinline__ float gelu_f(float x) {
    return 0.5f * x * (1.0f + erff(x * 0.70710678118654752f));
}
__device__ __forceinline__ short f2bf(float f) {
    union { float f; unsigned u; } x; x.f = f;
    unsigned r = x.u + 0x7FFF + ((x.u >> 16) & 1);
    return (short)(r >> 16);
}
__device__ __forceinline__ float bf2f(short s) {
    union { unsigned u; float f; } x; x.u = ((unsigned)(unsigned short)s) << 16;
    return x.f;
}
// async global->LDS, 16B per lane; LDS dest is wave-uniform base + lane*16
__device__ __forceinline__ void gld16(const short* g, short* l) {
    __builtin_amdgcn_global_load_lds((const __attribute__((address_space(1))) void*)g,
                                     (__attribute__((address_space(3))) void*)l,
                                     16, 0, 0);
}

// ---- convert all 6 weight matrices to bf16 (layout [oc][k], k contiguous) ----
__global__ void wconv_kernel(const float* __restrict__ wq, const float* __restrict__ wk,
                             const float* __restrict__ wv, const float* __restrict__ wo,
                             const float* __restrict__ c1, const float* __restrict__ c2,
                             short* __restrict__ dst) {
    int idx = blockIdx.x * 256 + threadIdx.x;  // total 786432
    const float* src; int off;
    if (idx < 65536)       { src = wq; off = idx; }
    else if (idx < 131072) { src = wk; off = idx - 65536; }
    else if (idx < 196608) { src = wv; off = idx - 131072; }
    else if (idx < 262144) { src = wo; off = idx - 196608; }
    else if (idx < 524288) { src = c1; off = idx - 262144; }
    else                   { src = c2; off = idx - 524288; }
    dst[idx] = f2bf(src[off]);
}

// ---- prep for dwgelu: transpose dww to [tap][1024], fold dwb+BN2 to (sc,sh);
//      also zero the LN2 atomic-stat accumulator (runs before all GEMMs) ----
__global__ void dwprep_kernel(const float* __restrict__ dww, const float* __restrict__ dwb,
                              const float* __restrict__ g2, const float* __restrict__ b2,
                              const float* __restrict__ m2, const float* __restrict__ v2,
                              float* __restrict__ wt, float* __restrict__ sc2,
                              float* __restrict__ sh2, float* __restrict__ st2) {
    int cm = blockIdx.x * 256 + threadIdx.x;  // 1024
    if (blockIdx.x == 0 && threadIdx.x < 64) st2[threadIdx.x] = 0.f;
    float sc = g2[cm] * rsqrtf(v2[cm] + EPS_);
    sc2[cm] = sc;
    sh2[cm] = (dwb[cm] - m2[cm]) * sc + b2[cm];
    #pragma unroll
    for (int tap = 0; tap < 9; ++tap) wt[tap * 1024 + cm] = dww[cm * 9 + tap];
}

// ---- generic LN stats reduce: 32 blocks, each folds cnt (sum,sumsq) pairs ----
__global__ void lnreduce_kernel(const float* __restrict__ part, int cnt,
                                float* __restrict__ out) {
    int b = blockIdx.x;
    const float* p = part + (long)b * cnt * 2;
    float s = 0.f, s2 = 0.f;
    for (int i = threadIdx.x; i < cnt; i += 256) {
        s += p[i * 2];
        s2 += p[i * 2 + 1];
    }
    #pragma unroll
    for (int o = 32; o > 0; o >>= 1) {
        s += __shfl_down(s, o);
        s2 += __shfl_down(s2, o);
    }
    __shared__ float ss[4][2];
    int wv = threadIdx.x >> 6;
    if ((threadIdx.x & 63) == 0) { ss[wv][0] = s; ss[wv][1] = s2; }
    __syncthreads();
    if (threadIdx.x == 0) {
        out[b * 2]     = ss[0][0] + ss[1][0] + ss[2][0] + ss[3][0];
        out[b * 2 + 1] = ss[0][1] + ss[1][1] + ss[2][1] + ss[3][1];
    }
}

// ---- LPU: depthwise 3x3 + bias + residual (fp32 channel-major), per-block LN1 partials ----
__global__ void lpu_kernel(const float* __restrict__ x, const float* __restrict__ w,
                           const float* __restrict__ bias, float* __restrict__ out,
                           float* __restrict__ part) {
    int idx = blockIdx.x * blockDim.x + threadIdx.x;
    int p = idx % NPIX;
    int c = (idx / NPIX) % C_;
    int y = p / W_, xx = p % W_;
    const float* xb = x + (size_t)(idx - p);
    const float* wc = w + c * 9;
    float acc = bias[c] + x[idx];
    #pragma unroll
    for (int dy = -1; dy <= 1; ++dy) {
        int yy = y + dy;
        if (yy < 0 || yy >= H_) continue;
        #pragma unroll
        for (int dx = -1; dx <= 1; ++dx) {
            int xc = xx + dx;
            if (xc < 0 || xc >= W_) continue;
            acc += wc[(dy + 1) * 3 + (dx + 1)] * xb[yy * W_ + xc];
        }
    }
    out[idx] = acc;
    float s = acc, s2 = acc * acc;
    #pragma unroll
    for (int o = 32; o > 0; o >>= 1) {
        s += __shfl_down(s, o);
        s2 += __shfl_down(s2, o);
    }
    __shared__ float ss[4][2];
    int wv = threadIdx.x >> 6;
    if ((threadIdx.x & 63) == 0) { ss[wv][0] = s; ss[wv][1] = s2; }
    __syncthreads();
    if (threadIdx.x == 0) {
        part[blockIdx.x * 2]     = ss[0][0] + ss[1][0] + ss[2][0] + ss[3][0];
        part[blockIdx.x * 2 + 1] = ss[0][1] + ss[1][1] + ss[2][1] + ss[3][1];
    }
}

// ---- transpose + LayerNorm: fp32 [b][256][784] -> bf16 [b][784][256] ----
__global__ void tln_kernel(const float* __restrict__ X, const float* __restrict__ st,
                           short* __restrict__ Y) {
    __shared__ float tile[32][33];
    int p0 = blockIdx.x * 32, c0 = blockIdx.y * 32, b = blockIdx.z;
    int tr = threadIdx.x >> 5, tc = threadIdx.x & 31;
    #pragma unroll
    for (int r = 0; r < 4; ++r) {
        int c = c0 + tr + r * 8, p = p0 + tc;
        tile[tr + r * 8][tc] = (p < NPIX) ? X[((long)b * C_ + c) * NPIX + p] : 0.f;
    }
    float sm = st[b * 2] * LN_INVN;
    float lr = rsqrtf(st[b * 2 + 1] * LN_INVN - sm * sm + EPS_);
    __syncthreads();
    #pragma unroll
    for (int r = 0; r < 4; ++r) {
        int p = p0 + tr + r * 8, c = c0 + tc;
        if (p < NPIX) Y[((long)b * NPIX + p) * C_ + c] = f2bf((tile[tc][tr + r * 8] - sm) * lr);
    }
}

// ---- kv depthwise 2x2 stride-2 (x1 fp32 channel-major -> bf16 pixel-major) ----
__global__ void kvconv_kernel(const float* __restrict__ x1, const float* __restrict__ w,
                              const float* __restrict__ bias, short* __restrict__ out) {
    int idx = blockIdx.x * 256 + threadIdx.x;
    if (idx >= B_ * NKPIX * C_) return;
    int c = idx & 255;
    int rest = idx >> 8;
    int p = rest % NKPIX;
    int b = rest / NKPIX;
    int yo = p / HK, xo = p % HK;
    const float* xb = x1 + ((long)b * C_ + c) * NPIX;
    const float* wc = w + c * 4;
    float a = bias[c]
            + wc[0] * xb[(2 * yo) * W_ + 2 * xo]     + wc[1] * xb[(2 * yo) * W_ + 2 * xo + 1]
            + wc[2] * xb[(2 * yo + 1) * W_ + 2 * xo] + wc[3] * xb[(2 * yo + 1) * W_ + 2 * xo + 1];
    out[idx] = f2bf(a);
}

// ---- MFMA GEMM, batch-merged M, 2-phase double-buffered global_load_lds:
//      issue next K-tile's loads BEFORE computing current tile; ONE barrier
//      per K-step (compiler's vmcnt(0)-before-barrier lands after compute).
//      16B-slot XOR swizzle via pre-swizzled global source -> 2-way (free)
//      ds_read_b128 bank pattern. M always a multiple of 128: no predication. ----
template <int EPI>
__global__ __launch_bounds__(256) void mfma_gemm(
    const short* __restrict__ Act, const short* __restrict__ Wb,
    int M, int N, int K,
    const float* __restrict__ bias,
    const float* __restrict__ g, const float* __restrict__ bb,
    const float* __restrict__ mm, const float* __restrict__ vv,
    const float* __restrict__ res, float* __restrict__ opart,
    short* __restrict__ outh, float* __restrict__ outf) {
    __shared__ short As[2 * 128 * 32];
    __shared__ short Bs[2 * 128 * 32];
    __shared__ float red[16][3];
    const int t = threadIdx.x;
    const int m0 = blockIdx.x * 128;
    const int n0 = blockIdx.y * 128;
    const int w = t >> 6, lane = t & 63;
    const int wm = (w & 1) * 64, wn = (w >> 1) * 64;
    const int col = lane & 15, quad = lane >> 4;

    float4_ acc[4][4];
    #pragma unroll
    for (int i = 0; i < 4; ++i)
        #pragma unroll
        for (int j = 0; j < 4; ++j)
            acc[i][j] = (float4_){0.f, 0.f, 0.f, 0.f};

    // staging: wave w loads rows [w*16,+16) and [w*16+64,+16) of A and B.
    // lane l -> row = chunkbase + l/4, 16B slot (l&3); global source slot is
    // XOR-swizzled by f(row) = (row ^ (row>>2)) & 3, which for chunkbase%16==0
    // reduces to a lane-constant: f = ((l>>2) ^ (l>>4)) & 3.
    const int l4 = lane >> 2;
    const int segsw = (lane & 3) ^ ((l4 ^ (l4 >> 2)) & 3);
    const short* gA = Act + (long)(m0 + w * 16 + l4) * K + segsw * 8;
    const short* gB = Wb  + (long)(n0 + w * 16 + l4) * K + segsw * 8;
    const long rs64 = (long)64 * K;
    const int woff = w * 512;   // w*16 rows * 32 shorts

    const int nk = K >> 5;
    // prologue: stage K-tile 0 into buffer 0
    {
        short* dA = As + woff;
        short* dB = Bs + woff;
        gld16(gA, dA);
        gld16(gA + rs64, dA + 2048);
        gld16(gB, dB);
        gld16(gB + rs64, dB + 2048);
    }
    // frag read slot: quad XOR-ed with f(row); row = wm|wn + i*16 + col makes
    // f = ((col&3) ^ ((col>>2)&3)) -- lane-constant.
    const int slotsw = (quad ^ ((col & 3) ^ ((col >> 2) & 3))) * 8;

    for (int kt = 0; kt < nk; ++kt) {
        __syncthreads();   // buf[kt&1] staged (vmcnt drained); prev reads done
        const int cur = (kt & 1) * 4096;
        if (kt + 1 < nk) {
            const int nxtoff = ((kt + 1) & 1) * 4096 + woff;
            const int k0 = (kt + 1) * 32;
            gld16(gA + k0, As + nxtoff);
            gld16(gA + rs64 + k0, As + nxtoff + 2048);
            gld16(gB + k0, Bs + nxtoff);
            gld16(gB + rs64 + k0, Bs + nxtoff + 2048);
        }
        short8 af[4], bf[4];
        #pragma unroll
        for (int i = 0; i < 4; ++i)
            af[i] = *(const short8*)(As + cur + (wm + i * 16 + col) * 32 + slotsw);
        #pragma unroll
        for (int j = 0; j < 4; ++j)
            bf[j] = *(const short8*)(Bs + cur + (wn + j * 16 + col) * 32 + slotsw);
        #pragma unroll
        for (int i = 0; i < 4; ++i)
            #pragma unroll
            for (int j = 0; j < 4; ++j)
                acc[i][j] = __builtin_amdgcn_mfma_f32_16x16x32_bf16(af[i], bf[j], acc[i][j], 0, 0, 0);
    }

    #pragma unroll
    for (int i = 0; i < 4; ++i) {
        const int pbase = m0 + wm + i * 16 + quad * 4;   // global row (b*784+p)
        float s1 = 0.f, s2s = 0.f;
        int bsmp = 0, psmp = 0;
        if (EPI == 3) { bsmp = pbase / NPIX; psmp = pbase - bsmp * NPIX; }
        #pragma unroll
        for (int j = 0; j < 4; ++j) {
            const int oc = n0 + wn + j * 16 + col;
            if (EPI == 0) {
                float cb = bias[oc];
                #pragma unroll
                for (int r = 0; r < 4; ++r)
                    outh[(long)(pbase + r) * N + oc] = f2bf(acc[i][j][r] + cb);
            } else if (EPI == 1) {
                float sc = g[oc] * rsqrtf(vv[oc] + EPS_);
                float sh = bb[oc] - mm[oc] * sc;
                float cb = bias[oc];
                #pragma unroll
                for (int r = 0; r < 4; ++r)
                    outh[(long)(pbase + r) * N + oc] =
                        f2bf(gelu_f((acc[i][j][r] + cb) * sc + sh));
            } else if (EPI == 2) {
                float cb = bias[oc];
                #pragma unroll
                for (int r = 0; r < 4; ++r) {
                    long jj = (long)(pbase + r) * 256 + oc;
                    float val = acc[i][j][r] + cb + res[jj];
                    outf[jj] = val;
                    s1 += val; s2s += val * val;
                }
            } else {
                float sc = g[oc] * rsqrtf(vv[oc] + EPS_);
                float sh = bb[oc] - mm[oc] * sc;
                float cb = bias[oc];
                long basei = ((long)bsmp * 256 + oc) * NPIX + psmp;
                float4 rv = *(const float4*)(res + basei);
                float4 y;
                y.x = (acc[i][j][0] + cb) * sc + sh + rv.x;
                y.y = (acc[i][j][1] + cb) * sc + sh + rv.y;
                y.z = (acc[i][j][2] + cb) * sc + sh + rv.z;
                y.w = (acc[i][j][3] + cb) * sc + sh + rv.w;
                *(float4*)(outf + basei) = y;
            }
        }
        if (EPI == 2) {
            // 16-row groups never straddle a sample (784 % 16 == 0):
            // full-wave reduce, then stash per-group sums for a block-level fold
            #pragma unroll
            for (int o = 32; o > 0; o >>= 1) {
                s1 += __shfl_down(s1, o);
                s2s += __shfl_down(s2s, o);
            }
            if (lane == 0) {
                red[w * 4 + i][0] = (float)(pbase / NPIX);
                red[w * 4 + i][1] = s1;
                red[w * 4 + i][2] = s2s;
            }
        }
    }
    if (EPI == 2) {
        // a 128-row tile touches at most 2 samples -> <=2 atomic pairs per block
        __syncthreads();
        if (t == 0) {
            int bsA = (int)red[0][0], bsB = -1;
            float a1 = 0.f, a2 = 0.f, b1 = 0.f, b2 = 0.f;
            #pragma unroll
            for (int e = 0; e < 16; ++e) {
                int bs = (int)red[e][0];
                if (bs == bsA) { a1 += red[e][1]; a2 += red[e][2]; }
                else           { bsB = bs; b1 += red[e][1]; b2 += red[e][2]; }
            }
            atomicAdd(&opart[bsA * 2], a1);
            atomicAdd(&opart[bsA * 2 + 1], a2);
            if (bsB >= 0) {
                atomicAdd(&opart[bsB * 2], b1);
                atomicAdd(&opart[bsB * 2 + 1], b2);
            }
        }
    }
}

// ---- MFMA flash attention v2: S^T trick ----
__global__ __launch_bounds__(256) void attn_kernel(const short* __restrict__ q,
                                                   const short* __restrict__ k,
                                                   const short* __restrict__ v,
                                                   const float* __restrict__ pos_b,
                                                   short* __restrict__ out) {
    __shared__ short Ks[224 * 40];   // [key][d], rows >=196 zero
    __shared__ short Vt[32 * 248];   // [d][key], cols >=196 zero
    __shared__ short Ps[128 * 72];   // [q][key-in-chunk(64)], per-wave rows
    __shared__ float Ls[128];        // 1/rowsum per q
    const int qt0 = blockIdx.x * 128;
    const int h = blockIdx.y;
    const int b = blockIdx.z;
    const int t = threadIdx.x;
    const short8 z8 = {0, 0, 0, 0, 0, 0, 0, 0};
    for (int e = t; e < 896; e += 256) {
        int row = e >> 2, seg = e & 3;
        short8 v8 = (row < NKPIX)
            ? *(const short8*)(k + ((long)(b * NKPIX + row)) * 256 + h * 32 + seg * 8) : z8;
        *(short8*)(Ks + row * 40 + seg * 8) = v8;
    }
    for (int e = t; e < 784; e += 256) {
        int key = e >> 2, seg = e & 3;
        short8 tv = *(const short8*)(v + ((long)(b * NKPIX + key)) * 256 + h * 32 + seg * 8);
        #pragma unroll
        for (int j = 0; j < 8; ++j) Vt[(seg * 8 + j) * 248 + key] = tv[j];
    }
    for (int e = t; e < 32 * 52; e += 256) {
        Vt[(e / 52) * 248 + 196 + (e % 52)] = 0;
    }
    __syncthreads();

    const int w = t >> 6, lane = t & 63;
    const int col = lane & 15, quad = lane >> 4;
    const float scale = 0.17677669529663689f;
    const float4_ z4 = {0.f, 0.f, 0.f, 0.f};

    short8 bq_[2];
    int qrow[2]; bool qvalid[2];
    #pragma unroll
    for (int i = 0; i < 2; ++i) {
        qrow[i] = qt0 + w * 32 + i * 16 + col;
        qvalid[i] = qrow[i] < NPIX;
        int qe = qvalid[i] ? qrow[i] : 0;
        bq_[i] = *(const short8*)(q + ((long)(b * NPIX + qe)) * 256 + h * 32 + quad * 8);
    }

    float4_ accO[2][2];
    #pragma unroll
    for (int i = 0; i < 2; ++i)
        #pragma unroll
        for (int nt = 0; nt < 2; ++nt) accO[i][nt] = z4;
    float lsum[2] = {0.f, 0.f};

    const int prow0 = w * 32;
    #pragma unroll
    for (int kc = 0; kc < 4; ++kc) {
        const int base = kc * 64;
        const int ntn = (kc == 3) ? 2 : 4;
        for (int nt = 0; nt < ntn; ++nt) {
            short8 afk = *(const short8*)(Ks + (base + nt * 16 + col) * 40 + quad * 8);
            int keybase = base + nt * 16 + quad * 4;
            bool kval = keybase < NKPIX;
            #pragma unroll
            for (int i = 0; i < 2; ++i) {
                float4_ s4 = __builtin_amdgcn_mfma_f32_16x16x32_bf16(afk, bq_[i], z4, 0, 0, 0);
                float4 pv = make_float4(0.f, 0.f, 0.f, 0.f);
                bool valid = kval && qvalid[i];
                if (valid)
                    pv = *(const float4*)(pos_b + ((long)h * NPIX + qrow[i]) * NKPIX + keybase);
                float p0 = valid ? __expf(s4[0] * scale + pv.x) : 0.f;
                float p1 = valid ? __expf(s4[1] * scale + pv.y) : 0.f;
                float p2 = valid ? __expf(s4[2] * scale + pv.z) : 0.f;
                float p3 = valid ? __expf(s4[3] * scale + pv.w) : 0.f;
                lsum[i] += p0 + p1 + p2 + p3;
                short4_ pk = {f2bf(p0), f2bf(p1), f2bf(p2), f2bf(p3)};
                *(short4_*)(Ps + (prow0 + i * 16 + col) * 72 + nt * 16 + quad * 4) = pk;
            }
        }
        const int ksn = (kc == 3) ? 1 : 2;
        for (int ks = 0; ks < ksn; ++ks) {
            #pragma unroll
            for (int i = 0; i < 2; ++i) {
                short8 afp = *(const short8*)(Ps + (prow0 + i * 16 + col) * 72 + ks * 32 + quad * 8);
                #pragma unroll
                for (int nt = 0; nt < 2; ++nt) {
                    short8 bfv = *(const short8*)(Vt + (nt * 16 + col) * 248 + base + ks * 32 + quad * 8);
                    accO[i][nt] = __builtin_amdgcn_mfma_f32_16x16x32_bf16(afp, bfv, accO[i][nt], 0, 0, 0);
                }
            }
        }
    }
    #pragma unroll
    for (int i = 0; i < 2; ++i) {
        float s = lsum[i];
        s += __shfl_xor(s, 16);
        s += __shfl_xor(s, 32);
        if (quad == 0) Ls[prow0 + i * 16 + col] = 1.f / s;
    }
    #pragma unroll
    for (int i = 0; i < 2; ++i) {
        int qb0 = qt0 + prow0 + i * 16 + quad * 4;
        #pragma unroll
        for (int r = 0; r < 4; ++r) {
            int qq = qb0 + r;
            if (qq >= NPIX) continue;
            float rinv = Ls[prow0 + i * 16 + quad * 4 + r];
            #pragma unroll
            for (int nt = 0; nt < 2; ++nt)
                out[((long)(b * NPIX + qq)) * 256 + h * 32 + nt * 16 + col] =
                    f2bf(accO[i][nt][r] * rinv);
        }
    }
}

// ---- dwconv3x3 + BN2 + GELU, 8 channels/thread via short8.
//      XCD-chunked block swizzle (T1): grid 12544 = 8*1568 exactly; each XCD
//      gets a contiguous (b,p) range so the 9x row reuse hits its own L2
//      instead of re-fetching from HBM (was 2.76x over-fetch). ----
__global__ __launch_bounds__(256) void dwgelu_kernel(
    const short* __restrict__ t2, const float* __restrict__ wt,
    const float* __restrict__ sc2, const float* __restrict__ sh2,
    short* __restrict__ t3) {
    const int nchunk = 12544 / 8;   // blocks per XCD chunk
    int bid = blockIdx.x;
    int swz = (bid & 7) * nchunk + (bid >> 3);   // bijective (12544 % 8 == 0)
    int idx = swz * 256 + threadIdx.x;  // B*NPIX*128 = 3,211,264
    int cm8 = idx & 127;
    int rest = idx >> 7;
    int p = rest % NPIX;
    int b = rest / NPIX;
    int py = p / W_, px = p % W_;
    int cm0 = cm8 * 8;
    const short* tb = t2 + ((long)b * NPIX) * CM + cm0;
    float acc[8];
    #pragma unroll
    for (int r = 0; r < 8; ++r) acc[r] = 0.f;
    #pragma unroll
    for (int dy = -1; dy <= 1; ++dy) {
        int yy = py + dy;
        if (yy < 0 || yy >= H_) continue;
        #pragma unroll
        for (int dx = -1; dx <= 1; ++dx) {
            int xc = px + dx;
            if (xc < 0 || xc >= W_) continue;
            int tap = (dy + 1) * 3 + (dx + 1);
            short8 tv = *(const short8*)(tb + (long)(yy * W_ + xc) * CM);
            float4 w0 = *(const float4*)(wt + tap * 1024 + cm0);
            float4 w1 = *(const float4*)(wt + tap * 1024 + cm0 + 4);
            acc[0] += bf2f(tv[0]) * w0.x;
            acc[1] += bf2f(tv[1]) * w0.y;
            acc[2] += bf2f(tv[2]) * w0.z;
            acc[3] += bf2f(tv[3]) * w0.w;
            acc[4] += bf2f(tv[4]) * w1.x;
            acc[5] += bf2f(tv[5]) * w1.y;
            acc[6] += bf2f(tv[6]) * w1.z;
            acc[7] += bf2f(tv[7]) * w1.w;
        }
    }
    float4 sa = *(const float4*)(sc2 + cm0);
    float4 sb = *(const float4*)(sc2 + cm0 + 4);
    float4 ha = *(const float4*)(sh2 + cm0);
    float4 hb = *(const float4*)(sh2 + cm0 + 4);
    short8 ov;
    ov[0] = f2bf(gelu_f(acc[0] * sa.x + ha.x));
    ov[1] = f2bf(gelu_f(acc[1] * sa.y + ha.y));
    ov[2] = f2bf(gelu_f(acc[2] * sa.z + ha.z));
    ov[3] = f2bf(gelu_f(acc[3] * sa.w + ha.w));
    ov[4] = f2bf(gelu_f(acc[4] * sb.x + hb.x));
    ov[5] = f2bf(gelu_f(acc[5] * sb.y + hb.y));
    ov[6] = f2bf(gelu_f(acc[6] * sb.z + hb.z));
    ov[7] = f2bf(gelu_f(acc[7] * sb.w + hb.w));
    *(short8*)(t3 + ((long)b * NPIX + p) * CM + cm0) = ov;
}

extern "C" void kernel_launch(void* const* d_in, const int* in_sizes, int n_in,
                              void* d_out, int out_size, void* d_ws, size_t ws_size,
                              hipStream_t stream) {
    const float* x     = (const float*)d_in[0];
    const float* lpu_w = (const float*)d_in[1];
    const float* lpu_b = (const float*)d_in[2];
    const float* dw_w  = (const float*)d_in[3];
    const float* dw_b  = (const float*)d_in[4];
    const float* wq    = (const float*)d_in[5];
    const float* bq    = (const float*)d_in[6];
    const float* wk    = (const float*)d_in[7];
    const float* bk    = (const float*)d_in[8];
    const float* wv    = (const float*)d_in[9];
    const float* bv    = (const float*)d_in[10];
    const float* wo    = (const float*)d_in[11];
    const float* bo    = (const float*)d_in[12];
    const float* posb  = (const float*)d_in[13];
    const float* c1_w  = (const float*)d_in[14];
    const float* c1_b  = (const float*)d_in[15];
    const float* bn1_g = (const float*)d_in[16];
    const float* bn1_b = (const float*)d_in[17];
    const float* bn1_m = (const float*)d_in[18];
    const float* bn1_v = (const float*)d_in[19];
    const float* dw2_w = (const float*)d_in[20];
    const float* dw2_b = (const float*)d_in[21];
    const float* bn2_g = (const float*)d_in[22];
    const float* bn2_b = (const float*)d_in[23];
    const float* bn2_m = (const float*)d_in[24];
    const float* bn2_v = (const float*)d_in[25];
    const float* c2_w  = (const float*)d_in[26];
    const float* c2_b  = (const float*)d_in[27];
    const float* bn3_g = (const float*)d_in[28];
    const float* bn3_b = (const float*)d_in[29];
    const float* bn3_m = (const float*)d_in[30];
    const float* bn3_v = (const float*)d_in[31];

    const long n1  = (long)B_ * C_ * NPIX;    // 6,422,528
    const long nkv = (long)B_ * C_ * NKPIX;   // 1,605,632
    const long nm  = (long)B_ * CM * NPIX;    // 25,690,112
    const int  nblk1 = (int)(n1 / 256);       // 25088 lpu blocks (784 per sample)
    const int  MQ = B_ * NPIX;                // 25088 = 196*128 (exact)
    const int  MKV = B_ * NKPIX;              // 6272  = 49*128  (exact)

    char* base = (char*)d_ws;
    float* x1   = (float*)base; base += n1 * 4;
    float* x2c  = (float*)base; base += n1 * 4;
    short* x1n  = (short*)base; base += n1 * 2;
    short* qb   = (short*)base; base += n1 * 2;
    short* tmpb = (short*)base; base += n1 * 2;
    short* t1n  = (short*)base; base += n1 * 2;
    short* kvb  = (short*)base; base += nkv * 2;
    short* kb   = (short*)base; base += nkv * 2;
    short* vb   = (short*)base; base += nkv * 2;
    short* t2   = (short*)base; base += nm * 2;
    short* t3   = (short*)base; base += nm * 2;
    short* wbf  = (short*)base; base += 786432L * 2;
    float* stats = (float*)base; base += 128 * 4;
    float* dwt   = (float*)base; base += 9216 * 4;   // [9][1024]
    float* dsc   = (float*)base; base += 1024 * 4;
    float* dsh   = (float*)base; base += 1024 * 4;
    float* part1 = (float*)base; base += (long)nblk1 * 2 * 4;
    float* outp = (float*)d_out;

    wconv_kernel<<<3072, 256, 0, stream>>>(wq, wk, wv, wo, c1_w, c2_w, wbf);
    dwprep_kernel<<<4, 256, 0, stream>>>(dw2_w, dw2_b, bn2_g, bn2_b, bn2_m, bn2_v,
                                         dwt, dsc, dsh, stats + 64);
    lpu_kernel<<<nblk1, 256, 0, stream>>>(x, lpu_w, lpu_b, x1, part1);
    lnreduce_kernel<<<B_, 256, 0, stream>>>(part1, nblk1 / B_, stats);
    kvconv_kernel<<<(int)((nkv + 255) / 256), 256, 0, stream>>>(x1, dw_w, dw_b, kvb);
    tln_kernel<<<dim3(25, 8, B_), 256, 0, stream>>>(x1, stats, x1n);
    // q/k/v projections (batch-merged M)
    mfma_gemm<0><<<dim3(MQ / 128, 2), 256, 0, stream>>>(
        x1n, wbf, MQ, 256, 256, bq, nullptr, nullptr, nullptr, nullptr,
        nullptr, nullptr, qb, nullptr);
    mfma_gemm<0><<<dim3(MKV / 128, 2), 256, 0, stream>>>(
        kvb, wbf + 65536, MKV, 256, 256, bk, nullptr, nullptr, nullptr, nullptr,
        nullptr, nullptr, kb, nullptr);
    mfma_gemm<0><<<dim3(MKV / 128, 2), 256, 0, stream>>>(
        kvb, wbf + 131072, MKV, 256, 256, bv, nullptr, nullptr, nullptr, nullptr,
        nullptr, nullptr, vb, nullptr);
    attn_kernel<<<dim3(7, 8, B_), 256, 0, stream>>>(qb, kb, vb, posb, tmpb);
    // wo + flat residual + LN2 stats via per-block-reduced atomics into stats+64
    mfma_gemm<2><<<dim3(MQ / 128, 2), 256, 0, stream>>>(
        tmpb, wbf + 196608, MQ, 256, 256, bo, nullptr, nullptr, nullptr, nullptr,
        x1, stats + 64, nullptr, x2c);
    tln_kernel<<<dim3(25, 8, B_), 256, 0, stream>>>(x2c, stats + 64, t1n);
    // conv1 1x1 + BN1 + GELU
    mfma_gemm<1><<<dim3(MQ / 128, 8), 256, 0, stream>>>(
        t1n, wbf + 262144, MQ, CM, 256, c1_b, bn1_g, bn1_b, bn1_m, bn1_v,
        nullptr, nullptr, t2, nullptr);
    dwgelu_kernel<<<(int)(B_ * NPIX * 128 / 256), 256, 0, stream>>>(t2, dwt, dsc, dsh, t3);
    // conv2 1x1 + BN3 + residual -> d_out (channel-major)
    mfma_gemm<3><<<dim3(MQ / 128, 2), 256, 0, stream>>>(
        t3, wbf + 524288, MQ, 256, 1024, c2_b, bn3_g, bn3_b, bn3_m, bn3_v,
        x2c, nullptr, nullptr, outp);
}